// Round 1
// baseline (350.342 us; speedup 1.0000x reference)
//
#include <hip/hip_runtime.h>
#include <hip/hip_bf16.h>

// LightGCNConv: out[dst] = sum_e w[e] * x[src_e], N=100000, d=64, E=1250000.
// One 64-lane wave per edge: lane i handles feature i. Gather and scatter are
// both fully-coalesced 256B row accesses. Scatter via fp32 atomicAdd
// (device-scope by default on CDNA — correct across XCDs).

#define N_NODES 100000
#define N_FEAT  64
#define N_EDGES 1250000

__global__ __launch_bounds__(256) void gnn_scatter_kernel(
    const float* __restrict__ x,        // [N, 64]
    const int*   __restrict__ ei,       // [2, E] row-major: src at [e], dst at [E+e]
    const float* __restrict__ w,        // [E]
    float*       __restrict__ out,      // [N, 64]
    int E) {
    const int waves_per_block = blockDim.x >> 6;            // 4
    const int e = blockIdx.x * waves_per_block + (threadIdx.x >> 6);
    const int lane = threadIdx.x & 63;
    if (e >= E) return;

    const int   src = ei[e];
    const int   dst = ei[E + e];
    const float wt  = w[e];

    const float v = wt * x[(size_t)src * N_FEAT + lane];
    atomicAdd(&out[(size_t)dst * N_FEAT + lane], v);
}

extern "C" void kernel_launch(void* const* d_in, const int* in_sizes, int n_in,
                              void* d_out, int out_size, void* d_ws, size_t ws_size,
                              hipStream_t stream) {
    const float* x  = (const float*)d_in[0];
    const int*   ei = (const int*)d_in[1];
    const float* w  = (const float*)d_in[2];
    float*       out = (float*)d_out;

    const int E = in_sizes[2];   // edge_weight has E elements

    // Harness poisons d_out with 0xAA; we accumulate, so zero it first.
    hipMemsetAsync(d_out, 0, (size_t)out_size * sizeof(float), stream);

    const int waves_per_block = 4;               // 256 threads
    const int blocks = (E + waves_per_block - 1) / waves_per_block;
    gnn_scatter_kernel<<<blocks, 256, 0, stream>>>(x, ei, w, out, E);
}

// Round 2
// 295.368 us; speedup vs baseline: 1.1861x; 1.1861x over previous
//
#include <hip/hip_runtime.h>
#include <hip/hip_bf16.h>

// LightGCNConv: out[dst] = sum_e w[e] * x[src_e], N=100000, d=64, E=1250000.
//
// R1 showed the naive scatter is atomic-throughput-bound: 80M fp32 device-scope
// atomicAdds write through L2 (WRITE_SIZE == E*256B == 320MB) at ~291G atomics/s.
// R2 strategy: build a dst-CSR in the workspace every call (histogram + 3-kernel
// scan + bucket fill, only 2.5M int atomics), then gather: one wave per dst node,
// lane = feature, accumulate in registers, write out exactly once.

#define N_NODES   100000
#define N_FEAT    64
#define SCAN_CHUNK 1024
#define NB        ((N_NODES + SCAN_CHUNK - 1) / SCAN_CHUNK)   // 98

// ---------------- CSR build ----------------

__global__ __launch_bounds__(256) void k_hist(
    const int* __restrict__ ei, int* __restrict__ cnt, int E) {
    int e = blockIdx.x * 256 + threadIdx.x;
    if (e >= E) return;
    atomicAdd(&cnt[ei[E + e]], 1);   // dst
}

// per-chunk (1024 elems) block sums
__global__ __launch_bounds__(256) void k_scan_reduce(
    const int* __restrict__ cnt, int* __restrict__ bsum) {
    __shared__ int red[256];
    int b = blockIdx.x, t = threadIdx.x;
    int s = 0;
    #pragma unroll
    for (int k = 0; k < 4; ++k) {
        int i = b * SCAN_CHUNK + k * 256 + t;
        if (i < N_NODES) s += cnt[i];
    }
    red[t] = s; __syncthreads();
    for (int off = 128; off > 0; off >>= 1) {
        if (t < off) red[t] += red[t + off];
        __syncthreads();
    }
    if (t == 0) bsum[b] = red[0];
}

// exclusive scan of NB (=98) block sums, in place — trivial single thread
__global__ __launch_bounds__(64) void k_scan_tops(int* __restrict__ bsum) {
    if (threadIdx.x != 0) return;
    int run = 0;
    for (int b = 0; b < NB; ++b) { int v = bsum[b]; bsum[b] = run; run += v; }
}

// per-chunk exclusive scan; writes offs[0..N]; zeros cnt for reuse as cursor
__global__ __launch_bounds__(256) void k_scan_down(
    int* __restrict__ cnt, const int* __restrict__ boffs, int* __restrict__ offs) {
    __shared__ int sdata[256];
    int b = blockIdx.x, t = threadIdx.x;
    int i0 = b * SCAN_CHUNK + t * 4;
    int vals[4];
    #pragma unroll
    for (int k = 0; k < 4; ++k) {
        int i = i0 + k;
        vals[k] = (i < N_NODES) ? cnt[i] : 0;
    }
    int tot = vals[0] + vals[1] + vals[2] + vals[3];
    sdata[t] = tot; __syncthreads();
    // Hillis-Steele inclusive scan of 256 per-thread totals
    for (int off = 1; off < 256; off <<= 1) {
        int v = (t >= off) ? sdata[t - off] : 0;
        __syncthreads();
        if (t >= off) sdata[t] += v;
        __syncthreads();
    }
    int excl = (t == 0) ? 0 : sdata[t - 1];
    int run = boffs[b] + excl;
    #pragma unroll
    for (int k = 0; k < 4; ++k) {
        int i = i0 + k;
        if (i < N_NODES) offs[i] = run;
        run += vals[k];
        if (i == N_NODES - 1) offs[N_NODES] = run;   // == E
    }
    #pragma unroll
    for (int k = 0; k < 4; ++k) {
        int i = i0 + k;
        if (i < N_NODES) cnt[i] = 0;                 // reset cursor
    }
}

// scatter edge payloads (src, w) into CSR slots
__global__ __launch_bounds__(256) void k_fill(
    const int* __restrict__ ei, const float* __restrict__ w,
    const int* __restrict__ offs, int* __restrict__ cur,
    int2* __restrict__ srcw, int E) {
    int e = blockIdx.x * 256 + threadIdx.x;
    if (e >= E) return;
    int dst = ei[E + e];
    int slot = offs[dst] + atomicAdd(&cur[dst], 1);
    srcw[slot] = make_int2(ei[e], __float_as_int(w[e]));
}

// ---------------- gather ----------------
// one wave per dst node; lane = feature index
__global__ __launch_bounds__(256) void k_gather(
    const float* __restrict__ x, const int* __restrict__ offs,
    const int2* __restrict__ srcw, float* __restrict__ out) {
    int node = blockIdx.x * 4 + (threadIdx.x >> 6);
    int lane = threadIdx.x & 63;
    if (node >= N_NODES) return;
    int beg = offs[node], end = offs[node + 1];
    float acc0 = 0.f, acc1 = 0.f;
    int j = beg;
    for (; j + 1 < end; j += 2) {
        int2 p0 = srcw[j];
        int2 p1 = srcw[j + 1];
        acc0 += __int_as_float(p0.y) * x[(size_t)p0.x * N_FEAT + lane];
        acc1 += __int_as_float(p1.y) * x[(size_t)p1.x * N_FEAT + lane];
    }
    if (j < end) {
        int2 p = srcw[j];
        acc0 += __int_as_float(p.y) * x[(size_t)p.x * N_FEAT + lane];
    }
    out[(size_t)node * N_FEAT + lane] = acc0 + acc1;
}

// ---------------- fallback (R1 atomic scatter) ----------------
__global__ __launch_bounds__(256) void gnn_scatter_kernel(
    const float* __restrict__ x, const int* __restrict__ ei,
    const float* __restrict__ w, float* __restrict__ out, int E) {
    int e = blockIdx.x * 4 + (threadIdx.x >> 6);
    int lane = threadIdx.x & 63;
    if (e >= E) return;
    float v = w[e] * x[(size_t)ei[e] * N_FEAT + lane];
    atomicAdd(&out[(size_t)ei[E + e] * N_FEAT + lane], v);
}

static inline size_t align16(size_t v) { return (v + 15) & ~(size_t)15; }

extern "C" void kernel_launch(void* const* d_in, const int* in_sizes, int n_in,
                              void* d_out, int out_size, void* d_ws, size_t ws_size,
                              hipStream_t stream) {
    const float* x   = (const float*)d_in[0];
    const int*   ei  = (const int*)d_in[1];
    const float* w   = (const float*)d_in[2];
    float*       out = (float*)d_out;
    const int E = in_sizes[2];

    // workspace layout
    size_t off_cnt  = 0;
    size_t off_offs = align16(off_cnt + (size_t)N_NODES * 4);
    size_t off_srcw = align16(off_offs + (size_t)(N_NODES + 1) * 4);
    size_t off_bsum = align16(off_srcw + (size_t)E * 8);
    size_t need     = off_bsum + (size_t)NB * 4;

    if (ws_size < need) {
        // fallback: R1 atomic scatter (350us) — only if workspace too small
        hipMemsetAsync(d_out, 0, (size_t)out_size * sizeof(float), stream);
        gnn_scatter_kernel<<<(E + 3) / 4, 256, 0, stream>>>(x, ei, w, out, E);
        return;
    }

    char* ws   = (char*)d_ws;
    int*  cnt  = (int*)(ws + off_cnt);
    int*  offs = (int*)(ws + off_offs);
    int2* srcw = (int2*)(ws + off_srcw);
    int*  bsum = (int*)(ws + off_bsum);

    hipMemsetAsync(cnt, 0, (size_t)N_NODES * 4, stream);
    k_hist<<<(E + 255) / 256, 256, 0, stream>>>(ei, cnt, E);
    k_scan_reduce<<<NB, 256, 0, stream>>>(cnt, bsum);
    k_scan_tops<<<1, 64, 0, stream>>>(bsum);
    k_scan_down<<<NB, 256, 0, stream>>>(cnt, bsum, offs);   // also zeros cnt
    k_fill<<<(E + 255) / 256, 256, 0, stream>>>(ei, w, offs, cnt, srcw, E);
    k_gather<<<(N_NODES + 3) / 4, 256, 0, stream>>>(x, offs, srcw, out);
}